// Round 9
// baseline (268.358 us; speedup 1.0000x reference)
//
#include <hip/hip_runtime.h>

// ---------------------------------------------------------------------------
// TripletLossWithHardMining  (B=4096, D=1024, fp32 in, fp32 scalar out)
//
//  K1 row_stats : wave-per-row; per-row constants; d_ap, d_an_row; bf16
//                 copies of a,p,n; init hard slots.
//  K2 gemm_mask : R13 = R12 resubmit (infra failed twice; audit found no
//                 race/deadlock/OOB; R9 precedent: identical resubmit ran).
//                 Hardening: LDS staging base now explicitly wave-uniform
//                 (wave*512 elems; HW adds lane*16B) matching R0/R3/R9's
//                 proven g2l pattern, instead of a per-lane pointer that
//                 relied on compiler readfirstlane.
//                 Structure: R0 restructured stage->COMPUTE->drain
//                 (T3-minimal). R0 was stage->drain->compute: g2l issued
//                 then immediately drained by the barrier -> full VMEM
//                 latency exposed every K-iter. R13: BK=32, double-buffered
//                 LDS (3 x 2 x 8KB = 48KB, 2 blocks/CU), one barrier/iter:
//                   STAGE(buf^1, tile t+1)   // 6 g2l, issued FIRST
//                   ds_read + 32 MFMA (buf)  // ~700+ cyc of compute
//                   __syncthreads()          // vmcnt(0) drain now ~free
//                 Unrolled x2 for static buffer indices. Swizzle for 64B
//                 rows: slot = chunk ^ ((row>>1)&3) (R9 measured 0 bank
//                 conflicts with this exact pattern). A stays in LDS
//                 (R11: L2-direct A was -30%). Epilogue identical to R0.
//  K3 finalize  : d_an = mean(hard_n), d_pp = mean(hard_p, inf->0),
//                 loss = mean(relu(d_ap - 0.5*d_pp - 0.5*d_an + 1)).
//
//  Dead-ends:
//   R4 barrier-free per-wave vmcnt(4):        184us, 15%
//   R5 fused 256x128 8-phase + vmcnt(0)/tile: 104us, 27%
//   R6 fused 256x128 4-phase counted:         107us, 26%
//   R7 unfused 128^2 2-barrier, 3 blk/CU:     104us, 27%
//   R9 unfused 256^2 k-half counted vmcnt(4): 117us, 24%
//   R10 A-direct + launch_bounds(256,3):      426us  REG SPILL artifact
//   R11 A-direct, no spill:                   126us, 21.5%  (A via L2 slower
//       than LDS -> staging right; R0's zero-distance drain is the target)
// ---------------------------------------------------------------------------

#define NB 4096
#define DIM 1024
#define EPSF 1e-6f
#define D_EPS2 (1024.0f * 1e-6f * 1e-6f)

#define BM 128           // block tile (rows and cols)
#define BK 32            // k-tile (bf16 elems) -> 64 B rows

typedef __bf16  bf16x8 __attribute__((ext_vector_type(8)));
typedef float   f32x4  __attribute__((ext_vector_type(4)));

__device__ __forceinline__ unsigned short f2bf(float x) {
    unsigned u = __float_as_uint(x);
    u += 0x7FFFu + ((u >> 16) & 1u);   // round-to-nearest-even
    return (unsigned short)(u >> 16);
}

// async 16B/lane global->LDS; lds base wave-uniform, data lands at base+lane*16
__device__ __forceinline__ void g2l16(const unsigned short* g, unsigned short* l) {
    __builtin_amdgcn_global_load_lds(
        (const __attribute__((address_space(1))) unsigned int*)g,
        (__attribute__((address_space(3))) unsigned int*)l, 16, 0, 0);
}

// stats layout (NB-float slots):
// 0: base_a[i] = |a_i|^2 + 2e*sum_a + D*e^2
// 1: cn[j]     = |n_j|^2 - 2e*sum_n
// 2: cp[j]     = |p_j|^2 - 2e*sum_p
// 3: d_ap   4: d_an_row   5: hard_n bits   6: hard_p bits

// wave-per-row: 1024 blocks x 4 waves; lane handles 4 float4 chunks per matrix
__global__ __launch_bounds__(256) void row_stats_kernel(
    const float* __restrict__ a, const float* __restrict__ p,
    const float* __restrict__ n,
    unsigned short* __restrict__ abf, unsigned short* __restrict__ pbf,
    unsigned short* __restrict__ nbf, float* __restrict__ stats)
{
    const int t    = threadIdx.x;
    const int wave = t >> 6, lane = t & 63;
    const int row  = blockIdx.x * 4 + wave;
    const size_t base = (size_t)row * DIM;

    const float4* a4 = (const float4*)(a + base);
    const float4* p4 = (const float4*)(p + base);
    const float4* n4 = (const float4*)(n + base);

    float v[8] = {0,0,0,0,0,0,0,0};   // sa qa sp qp sn qn dap2 dan2
#pragma unroll
    for (int c = 0; c < 4; c++) {
        const int idx = c * 64 + lane;
        const float4 va = a4[idx];
        const float4 vp = p4[idx];
        const float4 vn = n4[idx];
        const float fa[4] = {va.x, va.y, va.z, va.w};
        const float fp[4] = {vp.x, vp.y, vp.z, vp.w};
        const float fn[4] = {vn.x, vn.y, vn.z, vn.w};
#pragma unroll
        for (int e = 0; e < 4; e++) {
            v[0] += fa[e];           v[1] += fa[e] * fa[e];
            v[2] += fp[e];           v[3] += fp[e] * fp[e];
            v[4] += fn[e];           v[5] += fn[e] * fn[e];
            float dp = fa[e] - fp[e] + EPSF;  v[6] += dp * dp;
            float dn = fa[e] - fn[e] + EPSF;  v[7] += dn * dn;
        }
        ushort4 ba, bp, bn;
        ba.x = f2bf(fa[0]); ba.y = f2bf(fa[1]); ba.z = f2bf(fa[2]); ba.w = f2bf(fa[3]);
        bp.x = f2bf(fp[0]); bp.y = f2bf(fp[1]); bp.z = f2bf(fp[2]); bp.w = f2bf(fp[3]);
        bn.x = f2bf(fn[0]); bn.y = f2bf(fn[1]); bn.z = f2bf(fn[2]); bn.w = f2bf(fn[3]);
        ((ushort4*)(abf + base))[idx] = ba;
        ((ushort4*)(pbf + base))[idx] = bp;
        ((ushort4*)(nbf + base))[idx] = bn;
    }

#pragma unroll
    for (int m = 32; m >= 1; m >>= 1)
#pragma unroll
        for (int q = 0; q < 8; q++) v[q] += __shfl_xor(v[q], m);

    if (lane == 0) {
        stats[0 * NB + row] = v[1] + 2.0f * EPSF * v[0] + D_EPS2;  // base_a
        stats[1 * NB + row] = v[5] - 2.0f * EPSF * v[4];           // cn
        stats[2 * NB + row] = v[3] - 2.0f * EPSF * v[2];           // cp
        stats[3 * NB + row] = sqrtf(v[6]);                         // d_ap
        stats[4 * NB + row] = sqrtf(v[7]);                         // d_an_row
        ((unsigned*)stats)[5 * NB + row] = 0u;                     // hard_n
        ((unsigned*)stats)[6 * NB + row] = 0x7f800000u;            // hard_p
    }
}

// grid (32, 32): each block computes both A.N^T and A.P^T for its tile.
__global__ __launch_bounds__(256) void gemm_mask_kernel(
    const unsigned short* __restrict__ Abf,
    const unsigned short* __restrict__ Nbf,
    const unsigned short* __restrict__ Pbf,
    float* __restrict__ stats)
{
    const int i0 = blockIdx.x * BM;
    const int j0 = blockIdx.y * BM;

    __shared__ unsigned short sA[2][BM * BK];   // 2 x 8 KB
    __shared__ unsigned short sN[2][BM * BK];   // 2 x 8 KB
    __shared__ unsigned short sP[2][BM * BK];   // 2 x 8 KB -> 48 KB total

    const int t    = threadIdx.x;
    const int wave = t >> 6, lane = t & 63;
    const int wm   = wave >> 1, wn = wave & 1;
    const int quad = lane >> 4, lrow = lane & 15;

    // ---- staging: 256 thr x 16 B = 4 KB = 64 rows (of 128) per g2l round.
    // thread t -> row srow = t>>2 (+64*g), slot = t&3; physical slot s holds
    // logical 8-elem chunk s ^ ((row>>1)&3)  (pre-swizzled global source,
    // linear LDS dest; (row>>1)&3 is g-invariant since 64 % 8 == 0).
    // LDS base is wave-uniform (wave*512 elems); HW adds lane*16B, so
    // thread t's 16B land at byte t*16 = row(t>>2)*64B + slot(t&3)*16B.
    const int srow = t >> 2;                           // 0..63
    const int kch  = ((t & 3) ^ ((srow >> 1) & 3)) * 8;
    const unsigned short* gA = Abf + (size_t)(i0 + srow) * DIM + kch;
    const unsigned short* gN = Nbf + (size_t)(j0 + srow) * DIM + kch;
    const unsigned short* gP = Pbf + (size_t)(j0 + srow) * DIM + kch;
    const int lwav = wave * 512;                       // elems; + g*64*BK

    // ---- fragment read: logical chunk quad, physical quad^((lrow>>1)&3)
    // (rows im*16+lrow: (row>>1)&3 == (lrow>>1)&3 since im*16/2 % 4 == 0)
    // R9 measured SQ_LDS_BANK_CONFLICT = 0.0 with this exact pattern.
    const int rsw  = (quad ^ ((lrow >> 1) & 3)) * 8;
    const int aoff = (wm * 64 + lrow) * BK;
    const int boff = (wn * 64 + lrow) * BK;

    f32x4 accN[4][4], accP[4][4];
#pragma unroll
    for (int im = 0; im < 4; im++)
#pragma unroll
        for (int jn = 0; jn < 4; jn++) {
            accN[im][jn] = (f32x4)(0.0f);
            accP[im][jn] = (f32x4)(0.0f);
        }

// stage one BK=32 tile of all three matrices into buf B (6 g2l/thread)
#define STAGE(B, KT)                                                          \
    _Pragma("unroll")                                                         \
    for (int g = 0; g < 2; g++) {                                             \
        g2l16(gA + (size_t)(KT) + (size_t)(g * 64) * DIM,                     \
              &sA[B][g * 64 * BK + lwav]);                                    \
        g2l16(gN + (size_t)(KT) + (size_t)(g * 64) * DIM,                     \
              &sN[B][g * 64 * BK + lwav]);                                    \
        g2l16(gP + (size_t)(KT) + (size_t)(g * 64) * DIM,                     \
              &sP[B][g * 64 * BK + lwav]);                                    \
    }

// one K-tile's compute from buf B: 12 ds_read_b128 + 32 MFMA
#define COMPUTE(B)                                                            \
  {                                                                           \
    bf16x8 afr[4], bn_fr[4], bp_fr[4];                                        \
    _Pragma("unroll")                                                         \
    for (int im = 0; im < 4; im++)                                            \
        afr[im] = *(const bf16x8*)&sA[B][aoff + im * 16 * BK + rsw];          \
    _Pragma("unroll")                                                         \
    for (int jn = 0; jn < 4; jn++) {                                          \
        bn_fr[jn] = *(const bf16x8*)&sN[B][boff + jn * 16 * BK + rsw];        \
        bp_fr[jn] = *(const bf16x8*)&sP[B][boff + jn * 16 * BK + rsw];        \
    }                                                                         \
    _Pragma("unroll")                                                         \
    for (int im = 0; im < 4; im++)                                            \
        _Pragma("unroll")                                                     \
        for (int jn = 0; jn < 4; jn++) {                                      \
            accN[im][jn] = __builtin_amdgcn_mfma_f32_16x16x32_bf16(           \
                afr[im], bn_fr[jn], accN[im][jn], 0, 0, 0);                   \
            accP[im][jn] = __builtin_amdgcn_mfma_f32_16x16x32_bf16(           \
                afr[im], bp_fr[jn], accP[im][jn], 0, 0, 0);                   \
        }                                                                     \
  }

    // prologue: stage tile 0 into buf 0; barrier drains it (one-time cost)
    STAGE(0, 0);
    __syncthreads();

    // 32 K-tiles, unrolled x2 for static buffer indices.
    // Each iter: issue next-tile stage FIRST, then compute current tile,
    // then __syncthreads (its implicit vmcnt(0) retires loads that aged
    // under ~700+ cyc of MFMA -> drain ~free). Write-read safety: buf b is
    // staged only after the barrier that follows its last reader.
#pragma unroll 1
    for (int k2 = 0; k2 < 16; ++k2) {
        STAGE(1, (2 * k2 + 1) * BK);    // tile 2k2+1 -> buf1
        COMPUTE(0);                     // tile 2k2 from buf0
        __syncthreads();
        if (k2 < 15) STAGE(0, (2 * k2 + 2) * BK);   // tile 2k2+2 -> buf0
        COMPUTE(1);                     // tile 2k2+1 from buf1
        __syncthreads();
    }

#undef COMPUTE
#undef STAGE

    // epilogue: distances + masks + row reduce + atomics
    const float* __restrict__ base_a = stats + 0 * NB;
    const float* __restrict__ cn_v   = stats + 1 * NB;
    const float* __restrict__ cp_v   = stats + 2 * NB;
    const float* __restrict__ d_ap   = stats + 3 * NB;
    const float* __restrict__ d_an   = stats + 4 * NB;
    unsigned* __restrict__ hard_n = ((unsigned*)stats) + 5 * NB;
    unsigned* __restrict__ hard_p = ((unsigned*)stats) + 6 * NB;

#pragma unroll
    for (int im = 0; im < 4; im++) {
#pragma unroll
        for (int r = 0; r < 4; r++) {
            const int gi = i0 + wm * 64 + im * 16 + quad * 4 + r;
            const float cutN = d_ap[gi];
            const float cutP = d_an[gi];
            const float bi   = base_a[gi];
            float bestN = 0.0f;
            float bestP = __uint_as_float(0x7f800000u);
#pragma unroll
            for (int jn = 0; jn < 4; jn++) {
                const int gj = j0 + wn * 64 + jn * 16 + lrow;
                const float dN = sqrtf(fmaxf(bi + cn_v[gj] - 2.0f * accN[im][jn][r], 0.0f));
                const float dP = sqrtf(fmaxf(bi + cp_v[gj] - 2.0f * accP[im][jn][r], 0.0f));
                if (dN < cutN && dN > bestN) bestN = dN;
                if (dP > cutP && dP < bestP) bestP = dP;
            }
#pragma unroll
            for (int m = 1; m < 16; m <<= 1) {
                bestN = fmaxf(bestN, __shfl_xor(bestN, m));
                bestP = fminf(bestP, __shfl_xor(bestP, m));
            }
            if (lrow == 0) {
                const unsigned bn_ = __float_as_uint(bestN);
                const unsigned bp_ = __float_as_uint(bestP);
                if (bn_ != 0u)          atomicMax(hard_n + gi, bn_);
                if (bp_ != 0x7f800000u) atomicMin(hard_p + gi, bp_);
            }
        }
    }
}

__global__ __launch_bounds__(1024) void finalize_kernel(
    const float* __restrict__ stats, float* __restrict__ out)
{
    const unsigned* hard_n = ((const unsigned*)stats) + 5 * NB;
    const unsigned* hard_p = ((const unsigned*)stats) + 6 * NB;
    const float*    d_ap   = stats + 3 * NB;
    const int t = threadIdx.x;
    const int wave = t >> 6, lane = t & 63;
    __shared__ float pn[16], pp[16];
    __shared__ float s_dan, s_dpp;

    float sn = 0.0f, sp = 0.0f;
    for (int i = t; i < NB; i += 1024) {
        sn += __uint_as_float(hard_n[i]);
        const unsigned hp = hard_p[i];
        if (hp != 0x7f800000u) sp += __uint_as_float(hp);
    }
#pragma unroll
    for (int m = 32; m >= 1; m >>= 1) {
        sn += __shfl_xor(sn, m);
        sp += __shfl_xor(sp, m);
    }
    if (lane == 0) { pn[wave] = sn; pp[wave] = sp; }
    __syncthreads();
    if (t == 0) {
        float an = 0.0f, ap = 0.0f;
#pragma unroll
        for (int w = 0; w < 16; w++) { an += pn[w]; ap += pp[w]; }
        s_dan = an / (float)NB;
        s_dpp = ap / (float)NB;
    }
    __syncthreads();
    const float dan = s_dan, dpp = s_dpp;

    float accv = 0.0f;
    for (int i = t; i < NB; i += 1024)
        accv += fmaxf(d_ap[i] - 0.5f * dpp - 0.5f * dan + 1.0f, 0.0f);
#pragma unroll
    for (int m = 32; m >= 1; m >>= 1) accv += __shfl_xor(accv, m);
    if (lane == 0) pn[wave] = accv;
    __syncthreads();
    if (t == 0) {
        float s = 0.0f;
#pragma unroll
        for (int w = 0; w < 16; w++) s += pn[w];
        out[0] = s / (float)NB;
    }
}

extern "C" void kernel_launch(void* const* d_in, const int* in_sizes, int n_in,
                              void* d_out, int out_size, void* d_ws, size_t ws_size,
                              hipStream_t stream) {
    const float* a = (const float*)d_in[0];
    const float* p = (const float*)d_in[1];
    const float* n = (const float*)d_in[2];
    float* out = (float*)d_out;

    // ws layout: abf | pbf | nbf | stats(7*NB floats)  => ~25.3 MB
    unsigned short* abf = (unsigned short*)d_ws;
    unsigned short* pbf = abf + (size_t)NB * DIM;
    unsigned short* nbf = pbf + (size_t)NB * DIM;
    float* stats = (float*)(nbf + (size_t)NB * DIM);

    row_stats_kernel<<<NB / 4, 256, 0, stream>>>(a, p, n, abf, pbf, nbf, stats);

    dim3 grid(NB / BM, NB / BM);
    gemm_mask_kernel<<<grid, 256, 0, stream>>>(abf, nbf, pbf, stats);

    finalize_kernel<<<1, 1024, 0, stream>>>(stats, out);
}

// Round 10
// 196.821 us; speedup vs baseline: 1.3635x; 1.3635x over previous
//
#include <hip/hip_runtime.h>

// ---------------------------------------------------------------------------
// TripletLossWithHardMining  (B=4096, D=1024, fp32 in, fp32 scalar out)
//
//  K1 row_stats : wave-per-row; per-row constants; d_ap, d_an_row; bf16
//                 copies of a,p,n; init hard slots.
//  K2 gemm_mask : R14 = R13 (stage->COMPUTE->drain dbuf) with the VGPR
//                 pressure engineered back under the 2-waves/SIMD cliff.
//                 R13 failed on occupancy, not schedule: 160 arch VGPR +
//                 128 acc = 288 > 256 combined/wave -> 1 wave/SIMD (occ
//                 11.3%), latency hiding collapsed. R14 changes:
//                  (1) peeled tail (no conditional STAGE in the loop),
//                  (2) COMPUTE reuses one bfr[4] for N then P (frag
//                      pressure 48->32 VGPRs),
//                  (3) __launch_bounds__(256,2) pins the <=256 budget.
//                 Structure unchanged: BK=32, dbuf LDS 48KB, per iter
//                 STAGE(buf^1) FIRST, then 12 ds_read + 32 MFMA, then one
//                 __syncthreads (its vmcnt(0) drain retires loads aged
//                 under ~700 cyc of compute). Swizzle verified on HW
//                 (R13 absmax 0.0; R9 pattern: 0 bank conflicts).
//  K3 finalize  : d_an = mean(hard_n), d_pp = mean(hard_p, inf->0),
//                 loss = mean(relu(d_ap - 0.5*d_pp - 0.5*d_an + 1)).
//
//  Dead-ends:
//   R4 barrier-free per-wave vmcnt(4):        184us, 15%
//   R5 fused 256x128 8-phase + vmcnt(0)/tile: 104us, 27%
//   R6 fused 256x128 4-phase counted:         107us, 26%
//   R7 unfused 128^2 2-barrier, 3 blk/CU:     104us, 27%
//   R9 unfused 256^2 k-half counted vmcnt(4): 117us, 24%
//   R10 A-direct + launch_bounds(256,3):      426us  REG SPILL artifact
//   R11 A-direct, no spill:                   126us, 21.5% (A belongs in LDS)
//   R13 dbuf stage->compute->drain, 160 VGPR: 187us, 15% -- OCCUPANCY
//       artifact (288 combined regs > 256 -> 1 wave/SIMD). Fixed here.
// ---------------------------------------------------------------------------

#define NB 4096
#define DIM 1024
#define EPSF 1e-6f
#define D_EPS2 (1024.0f * 1e-6f * 1e-6f)

#define BM 128           // block tile (rows and cols)
#define BK 32            // k-tile (bf16 elems) -> 64 B rows

typedef __bf16  bf16x8 __attribute__((ext_vector_type(8)));
typedef float   f32x4  __attribute__((ext_vector_type(4)));

__device__ __forceinline__ unsigned short f2bf(float x) {
    unsigned u = __float_as_uint(x);
    u += 0x7FFFu + ((u >> 16) & 1u);   // round-to-nearest-even
    return (unsigned short)(u >> 16);
}

// async 16B/lane global->LDS; lds base wave-uniform, data lands at base+lane*16
__device__ __forceinline__ void g2l16(const unsigned short* g, unsigned short* l) {
    __builtin_amdgcn_global_load_lds(
        (const __attribute__((address_space(1))) unsigned int*)g,
        (__attribute__((address_space(3))) unsigned int*)l, 16, 0, 0);
}

// stats layout (NB-float slots):
// 0: base_a[i] = |a_i|^2 + 2e*sum_a + D*e^2
// 1: cn[j]     = |n_j|^2 - 2e*sum_n
// 2: cp[j]     = |p_j|^2 - 2e*sum_p
// 3: d_ap   4: d_an_row   5: hard_n bits   6: hard_p bits

// wave-per-row: 1024 blocks x 4 waves; lane handles 4 float4 chunks per matrix
__global__ __launch_bounds__(256) void row_stats_kernel(
    const float* __restrict__ a, const float* __restrict__ p,
    const float* __restrict__ n,
    unsigned short* __restrict__ abf, unsigned short* __restrict__ pbf,
    unsigned short* __restrict__ nbf, float* __restrict__ stats)
{
    const int t    = threadIdx.x;
    const int wave = t >> 6, lane = t & 63;
    const int row  = blockIdx.x * 4 + wave;
    const size_t base = (size_t)row * DIM;

    const float4* a4 = (const float4*)(a + base);
    const float4* p4 = (const float4*)(p + base);
    const float4* n4 = (const float4*)(n + base);

    float v[8] = {0,0,0,0,0,0,0,0};   // sa qa sp qp sn qn dap2 dan2
#pragma unroll
    for (int c = 0; c < 4; c++) {
        const int idx = c * 64 + lane;
        const float4 va = a4[idx];
        const float4 vp = p4[idx];
        const float4 vn = n4[idx];
        const float fa[4] = {va.x, va.y, va.z, va.w};
        const float fp[4] = {vp.x, vp.y, vp.z, vp.w};
        const float fn[4] = {vn.x, vn.y, vn.z, vn.w};
#pragma unroll
        for (int e = 0; e < 4; e++) {
            v[0] += fa[e];           v[1] += fa[e] * fa[e];
            v[2] += fp[e];           v[3] += fp[e] * fp[e];
            v[4] += fn[e];           v[5] += fn[e] * fn[e];
            float dp = fa[e] - fp[e] + EPSF;  v[6] += dp * dp;
            float dn = fa[e] - fn[e] + EPSF;  v[7] += dn * dn;
        }
        ushort4 ba, bp, bn;
        ba.x = f2bf(fa[0]); ba.y = f2bf(fa[1]); ba.z = f2bf(fa[2]); ba.w = f2bf(fa[3]);
        bp.x = f2bf(fp[0]); bp.y = f2bf(fp[1]); bp.z = f2bf(fp[2]); bp.w = f2bf(fp[3]);
        bn.x = f2bf(fn[0]); bn.y = f2bf(fn[1]); bn.z = f2bf(fn[2]); bn.w = f2bf(fn[3]);
        ((ushort4*)(abf + base))[idx] = ba;
        ((ushort4*)(pbf + base))[idx] = bp;
        ((ushort4*)(nbf + base))[idx] = bn;
    }

#pragma unroll
    for (int m = 32; m >= 1; m >>= 1)
#pragma unroll
        for (int q = 0; q < 8; q++) v[q] += __shfl_xor(v[q], m);

    if (lane == 0) {
        stats[0 * NB + row] = v[1] + 2.0f * EPSF * v[0] + D_EPS2;  // base_a
        stats[1 * NB + row] = v[5] - 2.0f * EPSF * v[4];           // cn
        stats[2 * NB + row] = v[3] - 2.0f * EPSF * v[2];           // cp
        stats[3 * NB + row] = sqrtf(v[6]);                         // d_ap
        stats[4 * NB + row] = sqrtf(v[7]);                         // d_an_row
        ((unsigned*)stats)[5 * NB + row] = 0u;                     // hard_n
        ((unsigned*)stats)[6 * NB + row] = 0x7f800000u;            // hard_p
    }
}

// grid (32, 32): each block computes both A.N^T and A.P^T for its tile.
__global__ __launch_bounds__(256, 2) void gemm_mask_kernel(
    const unsigned short* __restrict__ Abf,
    const unsigned short* __restrict__ Nbf,
    const unsigned short* __restrict__ Pbf,
    float* __restrict__ stats)
{
    const int i0 = blockIdx.x * BM;
    const int j0 = blockIdx.y * BM;

    __shared__ unsigned short sA[2][BM * BK];   // 2 x 8 KB
    __shared__ unsigned short sN[2][BM * BK];   // 2 x 8 KB
    __shared__ unsigned short sP[2][BM * BK];   // 2 x 8 KB -> 48 KB total

    const int t    = threadIdx.x;
    const int wave = t >> 6, lane = t & 63;
    const int wm   = wave >> 1, wn = wave & 1;
    const int quad = lane >> 4, lrow = lane & 15;

    // ---- staging: 256 thr x 16 B = 4 KB = 64 rows (of 128) per g2l round.
    // thread t -> row srow = t>>2 (+64*g), slot = t&3; physical slot s holds
    // logical 8-elem chunk s ^ ((row>>1)&3)  (pre-swizzled global source,
    // linear LDS dest; (row>>1)&3 is g-invariant since 64 % 8 == 0).
    // LDS base wave-uniform (wave*512 elems); HW adds lane*16B.
    const int srow = t >> 2;                           // 0..63
    const int kch  = ((t & 3) ^ ((srow >> 1) & 3)) * 8;
    const unsigned short* gA = Abf + (size_t)(i0 + srow) * DIM + kch;
    const unsigned short* gN = Nbf + (size_t)(j0 + srow) * DIM + kch;
    const unsigned short* gP = Pbf + (size_t)(j0 + srow) * DIM + kch;
    const int lwav = wave * 512;                       // elems; + g*64*BK

    // ---- fragment read: logical chunk quad, physical quad^((lrow>>1)&3)
    // (rows im*16+lrow: (row>>1)&3 == (lrow>>1)&3 since im*16/2 % 4 == 0)
    // R9/R13 measured 0 bank conflicts / absmax 0.0 with this pattern.
    const int rsw  = (quad ^ ((lrow >> 1) & 3)) * 8;
    const int aoff = (wm * 64 + lrow) * BK;
    const int boff = (wn * 64 + lrow) * BK;

    f32x4 accN[4][4], accP[4][4];
#pragma unroll
    for (int im = 0; im < 4; im++)
#pragma unroll
        for (int jn = 0; jn < 4; jn++) {
            accN[im][jn] = (f32x4)(0.0f);
            accP[im][jn] = (f32x4)(0.0f);
        }

// stage one BK=32 tile of all three matrices into buf B (6 g2l/thread)
#define STAGE(B, KT)                                                          \
    _Pragma("unroll")                                                         \
    for (int g = 0; g < 2; g++) {                                             \
        g2l16(gA + (size_t)(KT) + (size_t)(g * 64) * DIM,                     \
              &sA[B][g * 64 * BK + lwav]);                                    \
        g2l16(gN + (size_t)(KT) + (size_t)(g * 64) * DIM,                     \
              &sN[B][g * 64 * BK + lwav]);                                    \
        g2l16(gP + (size_t)(KT) + (size_t)(g * 64) * DIM,                     \
              &sP[B][g * 64 * BK + lwav]);                                    \
    }

// one K-tile's compute from buf B: 12 ds_read_b128 + 32 MFMA.
// Single bfr[4] reused for N then P: peak frag pressure 32 VGPRs (vs 48).
#define COMPUTE(B)                                                            \
  {                                                                           \
    bf16x8 afr[4], bfr[4];                                                    \
    _Pragma("unroll")                                                         \
    for (int im = 0; im < 4; im++)                                            \
        afr[im] = *(const bf16x8*)&sA[B][aoff + im * 16 * BK + rsw];          \
    _Pragma("unroll")                                                         \
    for (int jn = 0; jn < 4; jn++)                                            \
        bfr[jn] = *(const bf16x8*)&sN[B][boff + jn * 16 * BK + rsw];          \
    _Pragma("unroll")                                                         \
    for (int im = 0; im < 4; im++)                                            \
        _Pragma("unroll")                                                     \
        for (int jn = 0; jn < 4; jn++)                                        \
            accN[im][jn] = __builtin_amdgcn_mfma_f32_16x16x32_bf16(           \
                afr[im], bfr[jn], accN[im][jn], 0, 0, 0);                     \
    _Pragma("unroll")                                                         \
    for (int jn = 0; jn < 4; jn++)                                            \
        bfr[jn] = *(const bf16x8*)&sP[B][boff + jn * 16 * BK + rsw];          \
    _Pragma("unroll")                                                         \
    for (int im = 0; im < 4; im++)                                            \
        _Pragma("unroll")                                                     \
        for (int jn = 0; jn < 4; jn++)                                        \
            accP[im][jn] = __builtin_amdgcn_mfma_f32_16x16x32_bf16(           \
                afr[im], bfr[jn], accP[im][jn], 0, 0, 0);                     \
  }

    // prologue: stage tile 0 into buf 0; barrier drains it (one-time cost)
    STAGE(0, 0);
    __syncthreads();

    // 32 K-tiles: 15 full dbuf iterations + peeled tail (no conditionals ->
    // no duplicated live address state). Each iter: issue next-tile stage
    // FIRST, then compute current tile, then __syncthreads (its implicit
    // vmcnt(0) retires loads that aged under ~700 cyc of MFMA).
#pragma unroll 1
    for (int k2 = 0; k2 < 15; ++k2) {
        STAGE(1, (2 * k2 + 1) * BK);    // tile 2k2+1 -> buf1
        COMPUTE(0);                     // tile 2k2 from buf0
        __syncthreads();
        STAGE(0, (2 * k2 + 2) * BK);    // tile 2k2+2 -> buf0
        COMPUTE(1);                     // tile 2k2+1 from buf1
        __syncthreads();
    }
    // tail: tile 30 in buf0 (already staged), tile 31 -> buf1
    STAGE(1, 31 * BK);
    COMPUTE(0);                         // tile 30
    __syncthreads();
    COMPUTE(1);                         // tile 31

#undef COMPUTE
#undef STAGE

    // epilogue: distances + masks + row reduce + atomics
    const float* __restrict__ base_a = stats + 0 * NB;
    const float* __restrict__ cn_v   = stats + 1 * NB;
    const float* __restrict__ cp_v   = stats + 2 * NB;
    const float* __restrict__ d_ap   = stats + 3 * NB;
    const float* __restrict__ d_an   = stats + 4 * NB;
    unsigned* __restrict__ hard_n = ((unsigned*)stats) + 5 * NB;
    unsigned* __restrict__ hard_p = ((unsigned*)stats) + 6 * NB;

#pragma unroll
    for (int im = 0; im < 4; im++) {
#pragma unroll
        for (int r = 0; r < 4; r++) {
            const int gi = i0 + wm * 64 + im * 16 + quad * 4 + r;
            const float cutN = d_ap[gi];
            const float cutP = d_an[gi];
            const float bi   = base_a[gi];
            float bestN = 0.0f;
            float bestP = __uint_as_float(0x7f800000u);
#pragma unroll
            for (int jn = 0; jn < 4; jn++) {
                const int gj = j0 + wn * 64 + jn * 16 + lrow;
                const float dN = sqrtf(fmaxf(bi + cn_v[gj] - 2.0f * accN[im][jn][r], 0.0f));
                const float dP = sqrtf(fmaxf(bi + cp_v[gj] - 2.0f * accP[im][jn][r], 0.0f));
                if (dN < cutN && dN > bestN) bestN = dN;
                if (dP > cutP && dP < bestP) bestP = dP;
            }
#pragma unroll
            for (int m = 1; m < 16; m <<= 1) {
                bestN = fmaxf(bestN, __shfl_xor(bestN, m));
                bestP = fminf(bestP, __shfl_xor(bestP, m));
            }
            if (lrow == 0) {
                const unsigned bn_ = __float_as_uint(bestN);
                const unsigned bp_ = __float_as_uint(bestP);
                if (bn_ != 0u)          atomicMax(hard_n + gi, bn_);
                if (bp_ != 0x7f800000u) atomicMin(hard_p + gi, bp_);
            }
        }
    }
}

__global__ __launch_bounds__(1024) void finalize_kernel(
    const float* __restrict__ stats, float* __restrict__ out)
{
    const unsigned* hard_n = ((const unsigned*)stats) + 5 * NB;
    const unsigned* hard_p = ((const unsigned*)stats) + 6 * NB;
    const float*    d_ap   = stats + 3 * NB;
    const int t = threadIdx.x;
    const int wave = t >> 6, lane = t & 63;
    __shared__ float pn[16], pp[16];
    __shared__ float s_dan, s_dpp;

    float sn = 0.0f, sp = 0.0f;
    for (int i = t; i < NB; i += 1024) {
        sn += __uint_as_float(hard_n[i]);
        const unsigned hp = hard_p[i];
        if (hp != 0x7f800000u) sp += __uint_as_float(hp);
    }
#pragma unroll
    for (int m = 32; m >= 1; m >>= 1) {
        sn += __shfl_xor(sn, m);
        sp += __shfl_xor(sp, m);
    }
    if (lane == 0) { pn[wave] = sn; pp[wave] = sp; }
    __syncthreads();
    if (t == 0) {
        float an = 0.0f, ap = 0.0f;
#pragma unroll
        for (int w = 0; w < 16; w++) { an += pn[w]; ap += pp[w]; }
        s_dan = an / (float)NB;
        s_dpp = ap / (float)NB;
    }
    __syncthreads();
    const float dan = s_dan, dpp = s_dpp;

    float accv = 0.0f;
    for (int i = t; i < NB; i += 1024)
        accv += fmaxf(d_ap[i] - 0.5f * dpp - 0.5f * dan + 1.0f, 0.0f);
#pragma unroll
    for (int m = 32; m >= 1; m >>= 1) accv += __shfl_xor(accv, m);
    if (lane == 0) pn[wave] = accv;
    __syncthreads();
    if (t == 0) {
        float s = 0.0f;
#pragma unroll
        for (int w = 0; w < 16; w++) s += pn[w];
        out[0] = s / (float)NB;
    }
}

extern "C" void kernel_launch(void* const* d_in, const int* in_sizes, int n_in,
                              void* d_out, int out_size, void* d_ws, size_t ws_size,
                              hipStream_t stream) {
    const float* a = (const float*)d_in[0];
    const float* p = (const float*)d_in[1];
    const float* n = (const float*)d_in[2];
    float* out = (float*)d_out;

    // ws layout: abf | pbf | nbf | stats(7*NB floats)  => ~25.3 MB
    unsigned short* abf = (unsigned short*)d_ws;
    unsigned short* pbf = abf + (size_t)NB * DIM;
    unsigned short* nbf = pbf + (size_t)NB * DIM;
    float* stats = (float*)(nbf + (size_t)NB * DIM);

    row_stats_kernel<<<NB / 4, 256, 0, stream>>>(a, p, n, abf, pbf, nbf, stats);

    dim3 grid(NB / BM, NB / BM);
    gemm_mask_kernel<<<grid, 256, 0, stream>>>(abf, nbf, pbf, stats);

    finalize_kernel<<<1, 1024, 0, stream>>>(stats, out);
}